// Round 7
// baseline (309.027 us; speedup 1.0000x reference)
//
#include <hip/hip_runtime.h>

// PseudoImageScatter: img[f, y, x] = pillar_features[p, f], last pillar wins.
// Pass 1: winner[y*W+x] = atomicMax(pillar idx)  (last-wins == max idx)
// Pass 2: 256-cell tiles, feature-major LDS transpose, two f-halves of 32.
//   LDS zeroed ONCE (vectorized, conflict-free); only occupied cells (~10%)
//   ever write it after that — phase A gather is exec-masked sparse (cheap).
//   Phase B: ds_read_b128 + 1 KiB contiguous PLAIN float4 store per wave instr
//   (R6 used nontemporal stores: NT acks memory-side, so the compiler's
//    vmcnt(0)-before-barrier drained 8 KiB/wave to HBM every half, and NT
//    defeats L2 write-combining. Plain stores ack at L2 — fast barrier cross,
//    lazy write-back, same path the 6.3 TB/s fillBuffer uses.)

constexpr int H    = 1024;
constexpr int W    = 1024;
constexpr int HW   = H * W;
constexpr int NF   = 64;
constexpr int TILE = 256;           // cells per block
constexpr int HALF = 32;            // features per LDS pass

__global__ void winner_kernel(const int* __restrict__ coords,
                              int* __restrict__ winner, int np) {
    int p = blockIdx.x * blockDim.x + threadIdx.x;
    if (p >= np) return;
    int y = coords[p * 3 + 1];
    int x = coords[p * 3 + 2];
    if ((unsigned)x < (unsigned)W && (unsigned)y < (unsigned)H) {
        atomicMax(winner + (y * W + x), p);   // device-scope, cross-XCD safe
    }
}

__global__ void __launch_bounds__(256, 4) fill_kernel(const float* __restrict__ feat,
                                                      const int* __restrict__ winner,
                                                      float* __restrict__ out) {
    __shared__ float lds[HALF * TILE];        // 32 KiB, f-major -> 4 blocks/CU

    const int base = blockIdx.x * TILE;
    const int t    = threadIdx.x;             // == cell within tile (phase A)
    const int wv   = t >> 6;                  // wave 0..3
    const int l    = t & 63;                  // lane

    const int wp = winner[base + t];          // coalesced

    // ---- Zero LDS once. Empty columns are never touched again, so they
    // stay zero for BOTH halves.
    {
        float4 z = {0.0f, 0.0f, 0.0f, 0.0f};
#pragma unroll
        for (int j = 0; j < 8; ++j)
            *(float4*)&lds[j * 1024 + t * 4] = z;
    }
    __syncthreads();

    const float4* row = (const float4*)(feat + (size_t)max(wp, 0) * NF);

    for (int h = 0; h < 2; ++h) {
        // ---- Phase A: occupied threads (~10%, exec-masked) stage 32 features
        // of their cell, f-major. bank = t%32 per instr -> 2-way = free.
        if (wp >= 0) {
#pragma unroll
            for (int j = 0; j < 8; ++j) {
                float4 r = row[h * 8 + j];
                lds[(j * 4 + 0) * TILE + t] = r.x;
                lds[(j * 4 + 1) * TILE + t] = r.y;
                lds[(j * 4 + 2) * TILE + t] = r.z;
                lds[(j * 4 + 3) * TILE + t] = r.w;
            }
        }
        __syncthreads();

        // ---- Phase B: wave wv writes plane f = h*32 + p*4 + wv, cells
        // base..base+255: 64 lanes x 16 B = 1 KiB contiguous per instr.
#pragma unroll
        for (int p = 0; p < 8; ++p) {
            const int floc = p * 4 + wv;
            float4 v = *(const float4*)&lds[floc * TILE + l * 4];
            *(float4*)(out + (size_t)(h * HALF + floc) * HW + base + l * 4) = v;
        }
        __syncthreads();   // B(h) must finish before A(h+1) overwrites columns
    }
}

extern "C" void kernel_launch(void* const* d_in, const int* in_sizes, int n_in,
                              void* d_out, int out_size, void* d_ws, size_t ws_size,
                              hipStream_t stream) {
    const float* feat   = (const float*)d_in[0];
    const int*   coords = (const int*)d_in[1];
    float*       out    = (float*)d_out;
    int np = in_sizes[1] / 3;

    int* winner = (int*)d_ws;   // HW ints = 4 MiB scratch

    (void)hipMemsetAsync(winner, 0xFF, (size_t)HW * sizeof(int), stream);  // winner := -1
    winner_kernel<<<(np + 255) / 256, 256, 0, stream>>>(coords, winner, np);
    fill_kernel<<<HW / TILE, 256, 0, stream>>>(feat, winner, out);
}